// Round 1
// baseline (715.085 us; speedup 1.0000x reference)
//
#include <hip/hip_runtime.h>
#include <stdint.h>

#define NB    65536
#define BATCH 4
#define TOPN  1000
#define MMAX  2048
#define THRESH 0.974f
#define NEGV  (-1e9f)
#define NMS_T 0.7f

// ctrs layout (uint32): [0..3]=cand count per image, [4..7]=max coord bits, [8..11]=fallback flag

__device__ __forceinline__ void decode_box(const float* __restrict__ anchors,
                                           const float* __restrict__ deltas,
                                           int b, int i, float wmax, float hmax,
                                           float& x1, float& y1, float& x2, float& y2) {
  float a0 = anchors[4*i+0], a1 = anchors[4*i+1], a2v = anchors[4*i+2], a3 = anchors[4*i+3];
  float ws = a2v - a0 + 1.0f;
  float hs = a3 - a1 + 1.0f;
  float cx = a0 + 0.5f*ws;
  float cy = a1 + 0.5f*hs;
  const float* d = deltas + ((size_t)b*NB + (size_t)i)*4;
  float dx = d[0], dy = d[1], dw = d[2], dh = d[3];
  float pcx = dx*ws + cx;
  float pcy = dy*hs + cy;
  float pw = expf(dw)*ws;
  float ph = expf(dh)*hs;
  x1 = pcx - 0.5f*pw; y1 = pcy - 0.5f*ph;
  x2 = pcx + 0.5f*pw; y2 = pcy + 0.5f*ph;
  x1 = fminf(fmaxf(x1, 0.0f), wmax);
  y1 = fminf(fmaxf(y1, 0.0f), hmax);
  x2 = fminf(fmaxf(x2, 0.0f), wmax);
  y2 = fminf(fmaxf(y2, 0.0f), hmax);
}

__global__ void k_init(uint32_t* ctrs) {
  int t = threadIdx.x;
  if (t < 12) ctrs[t] = 0u;
}

__global__ void k_prep(const float* __restrict__ scores, const float* __restrict__ deltas,
                       const float* __restrict__ anchors, const float* __restrict__ im_info,
                       uint32_t* ctrs, unsigned long long* keys) {
  int b = blockIdx.y;
  int i = blockIdx.x * 256 + threadIdx.x;
  float wmax = im_info[b*3+1] - 1.0f;
  float hmax = im_info[b*3+0] - 1.0f;
  float x1, y1, x2, y2;
  decode_box(anchors, deltas, b, i, wmax, hmax, x1, y1, x2, y2);
  float m = fmaxf(fmaxf(x1, y1), fmaxf(x2, y2));
  __shared__ float red[256];
  red[threadIdx.x] = m;
  __syncthreads();
  for (int s = 128; s > 0; s >>= 1) {
    if (threadIdx.x < s) red[threadIdx.x] = fmaxf(red[threadIdx.x], red[threadIdx.x + s]);
    __syncthreads();
  }
  if (threadIdx.x == 0) atomicMax(&ctrs[4+b], __float_as_uint(red[0]));
  float sc = scores[(size_t)b*NB + i];
  if (sc >= THRESH) {
    uint32_t slot = atomicAdd(&ctrs[b], 1u);
    if (slot < (uint32_t)MMAX) {
      unsigned long long key = ((unsigned long long)(~__float_as_uint(sc)) << 32) | (uint32_t)i;
      keys[(size_t)b*MMAX + slot] = key;
    } else {
      ctrs[8+b] = 1u;  // overflow -> fallback
    }
  }
}

__global__ __launch_bounds__(1024) void k_sort(const uint32_t* __restrict__ ctrs,
                                               unsigned long long* keys) {
  int b = blockIdx.x;
  __shared__ unsigned long long sm[MMAX];
  int n = min((int)ctrs[b], MMAX);
  for (int i = threadIdx.x; i < MMAX; i += 1024)
    sm[i] = (i < n) ? keys[(size_t)b*MMAX + i] : ~0ULL;
  __syncthreads();
  for (int k = 2; k <= MMAX; k <<= 1) {
    for (int j = k >> 1; j > 0; j >>= 1) {
      for (int i = threadIdx.x; i < MMAX; i += 1024) {
        int ixj = i ^ j;
        if (ixj > i) {
          bool asc = ((i & k) == 0);
          unsigned long long a = sm[i], bb = sm[ixj];
          if ((a > bb) == asc) { sm[i] = bb; sm[ixj] = a; }
        }
      }
      __syncthreads();
    }
  }
  for (int i = threadIdx.x; i < n; i += 1024)
    keys[(size_t)b*MMAX + i] = sm[i];
}

__global__ __launch_bounds__(256) void k_nms(const float* __restrict__ deltas,
                                             const float* __restrict__ anchors,
                                             const float* __restrict__ im_info,
                                             const int* __restrict__ ids,
                                             uint32_t* ctrs,
                                             const unsigned long long* __restrict__ keys,
                                             float* __restrict__ out) {
  int b = blockIdx.x;
  int tid = threadIdx.x;
  __shared__ float cbox[MMAX][4];
  __shared__ uint8_t clev[MMAX];
  __shared__ uint32_t kout[TOPN];           // (level<<16) | slot
  __shared__ unsigned long long wmask[4];
  __shared__ uint32_t smat[128];            // [0..63]=lo word, [64..127]=hi word

  int n = min((int)ctrs[b], MMAX);
  float max_c = __uint_as_float(ctrs[4+b]) + 1.0f;
  float wmax = im_info[b*3+1] - 1.0f;
  float hmax = im_info[b*3+0] - 1.0f;

  for (int s = tid; s < n; s += 256) {
    unsigned long long key = keys[(size_t)b*MMAX + s];
    int i = (int)(uint32_t)key;
    float x1, y1, x2, y2;
    decode_box(anchors, deltas, b, i, wmax, hmax, x1, y1, x2, y2);
    int lv = ids[i];
    float off = (float)lv * max_c;
    cbox[s][0] = x1 + off; cbox[s][1] = y1 + off;
    cbox[s][2] = x2 + off; cbox[s][3] = y2 + off;
    clev[s] = (uint8_t)lv;
  }
  __syncthreads();

  int kept = 0;
  int chunkStart = 0;
  while (chunkStart < n && kept < TOPN) {
    if (tid < 128) smat[tid] = 0u;
    __syncthreads();  // B1

    int lane = tid & 63;
    int q = tid >> 6;
    int c = chunkStart + lane;
    bool sup = false;
    if (c < n) {
      float c0 = cbox[c][0], c1 = cbox[c][1], c2 = cbox[c][2], c3 = cbox[c][3];
      int clv = (int)clev[c];
      float ca = (c2 - c0) * (c3 - c1);
      for (int k = q; k < kept && !sup; k += 4) {
        uint32_t e = kout[k];
        if ((int)(e >> 16) != clv) continue;
        int s = (int)(e & 0xffffu);
        float k0 = cbox[s][0], k1 = cbox[s][1], k2 = cbox[s][2], k3 = cbox[s][3];
        float xx1 = fmaxf(k0, c0), yy1 = fmaxf(k1, c1);
        float xx2 = fminf(k2, c2), yy2 = fminf(k3, c3);
        float inter = fmaxf(xx2 - xx1, 0.0f) * fmaxf(yy2 - yy1, 0.0f);
        float a1 = (k2 - k0) * (k3 - k1);
        float iou = inter / fmaxf(a1 + ca - inter, 1e-6f);
        if (iou > NMS_T) sup = true;
      }
    }
    unsigned long long bal = __ballot(sup);
    if (lane == 0) wmask[q] = bal;

    // intra-chunk pairwise suppression matrix (i suppresses j>i)
    {
      int i = lane;
      int ci = chunkStart + i;
      if (ci < n) {
        float A0 = cbox[ci][0], A1 = cbox[ci][1], A2 = cbox[ci][2], A3 = cbox[ci][3];
        int alv = (int)clev[ci];
        float aar = (A2 - A0) * (A3 - A1);
        for (int j = i + 1 + q; j < 64; j += 4) {
          int cj = chunkStart + j;
          if (cj >= n) break;
          if ((int)clev[cj] != alv) continue;
          float B0 = cbox[cj][0], B1 = cbox[cj][1], B2 = cbox[cj][2], B3 = cbox[cj][3];
          float xx1 = fmaxf(A0, B0), yy1 = fmaxf(A1, B1);
          float xx2 = fminf(A2, B2), yy2 = fminf(A3, B3);
          float inter = fmaxf(xx2 - xx1, 0.0f) * fmaxf(yy2 - yy1, 0.0f);
          float a2r = (B2 - B0) * (B3 - B1);
          float iou = inter / fmaxf(aar + a2r - inter, 1e-6f);
          if (iou > NMS_T) {
            if (j < 32) atomicOr(&smat[i], 1u << j);
            else        atomicOr(&smat[64 + i], 1u << (j - 32));
          }
        }
      }
    }
    __syncthreads();  // B2

    // serial resolution (all threads redundantly, identical results)
    unsigned long long running = wmask[0] | wmask[1] | wmask[2] | wmask[3];
    int lim = min(64, n - chunkStart);
    for (int i = 0; i < lim && kept < TOPN; ++i) {
      if (!((running >> i) & 1ULL)) {
        int cc = chunkStart + i;
        kout[kept] = ((uint32_t)clev[cc] << 16) | (uint32_t)cc;
        kept++;
        running |= ((unsigned long long)smat[64 + i] << 32) | (unsigned long long)smat[i];
      }
    }
    __syncthreads();  // B3: protect smat/wmask reuse next chunk
    chunkStart += 64;
  }

  if (kept < TOPN) {
    if (tid == 0) ctrs[8+b] = 1u;  // exhausted candidates -> fallback
  }

  for (int t = tid; t < TOPN; t += 256) {
    size_t o = ((size_t)b * TOPN + t) * 5;
    if (t < kept) {
      uint32_t e = kout[t];
      int s = (int)(e & 0xffffu);
      int i = (int)(uint32_t)keys[(size_t)b*MMAX + s];
      float x1, y1, x2, y2;
      decode_box(anchors, deltas, b, i, wmax, hmax, x1, y1, x2, y2);
      out[o+0] = (float)b; out[o+1] = x1; out[o+2] = y1; out[o+3] = x2; out[o+4] = y2;
    } else {
      out[o+0] = (float)b; out[o+1] = 0.0f; out[o+2] = 0.0f; out[o+3] = 0.0f; out[o+4] = 0.0f;
    }
  }
}

// Exact brute-force greedy; runs only if flag set (expected: never).
__global__ __launch_bounds__(1024) void k_fallback(const float* __restrict__ scores,
                                                   const float* __restrict__ deltas,
                                                   const float* __restrict__ anchors,
                                                   const float* __restrict__ im_info,
                                                   const int* __restrict__ ids,
                                                   const uint32_t* __restrict__ ctrs,
                                                   float* smut, float* __restrict__ out) {
  int b = blockIdx.x;
  if (ctrs[8+b] == 0u) return;
  int tid = threadIdx.x;
  float max_c = __uint_as_float(ctrs[4+b]) + 1.0f;
  float wmax = im_info[b*3+1] - 1.0f;
  float hmax = im_info[b*3+0] - 1.0f;
  for (int i = tid; i < NB; i += 1024) smut[(size_t)b*NB + i] = scores[(size_t)b*NB + i];
  __shared__ float rv[1024];
  __shared__ int ri[1024];
  __syncthreads();
  for (int it = 0; it < TOPN; ++it) {
    float bv = -3e38f; int bi = 0x7fffffff;
    for (int i = tid; i < NB; i += 1024) {
      float v = smut[(size_t)b*NB + i];
      if (v > bv || (v == bv && i < bi)) { bv = v; bi = i; }
    }
    rv[tid] = bv; ri[tid] = bi;
    __syncthreads();
    for (int s = 512; s > 0; s >>= 1) {
      if (tid < s) {
        float v2 = rv[tid + s]; int i2 = ri[tid + s];
        if (v2 > rv[tid] || (v2 == rv[tid] && i2 < ri[tid])) { rv[tid] = v2; ri[tid] = i2; }
      }
      __syncthreads();
    }
    int ii = ri[0]; float vv = rv[0];
    bool valid = vv > NEGV * 0.5f;
    float x1, y1, x2, y2;
    decode_box(anchors, deltas, b, ii, wmax, hmax, x1, y1, x2, y2);
    int lv = ids[ii];
    float off = (float)lv * max_c;
    float s0 = x1 + off, s1 = y1 + off, s2 = x2 + off, s3 = y2 + off;
    float a1 = (s2 - s0) * (s3 - s1);
    if (tid == 0) {
      size_t o = ((size_t)b * TOPN + it) * 5;
      out[o+0] = (float)b;
      out[o+1] = valid ? x1 : 0.0f;
      out[o+2] = valid ? y1 : 0.0f;
      out[o+3] = valid ? x2 : 0.0f;
      out[o+4] = valid ? y2 : 0.0f;
    }
    for (int j = tid; j < NB; j += 1024) {
      float v = smut[(size_t)b*NB + j];
      if (v <= NEGV * 0.5f) continue;
      if (ids[j] != lv) continue;      // cross-level IoU is exactly 0 here
      float bx1, by1, bx2, by2;
      decode_box(anchors, deltas, b, j, wmax, hmax, bx1, by1, bx2, by2);
      float t0 = bx1 + off, t1 = by1 + off, t2 = bx2 + off, t3 = by2 + off;
      float xx1 = fmaxf(s0, t0), yy1 = fmaxf(s1, t1);
      float xx2 = fminf(s2, t2), yy2 = fminf(s3, t3);
      float inter = fmaxf(xx2 - xx1, 0.0f) * fmaxf(yy2 - yy1, 0.0f);
      float a2r = (t2 - t0) * (t3 - t1);
      float iou = inter / fmaxf(a1 + a2r - inter, 1e-6f);
      if (iou > NMS_T) smut[(size_t)b*NB + j] = NEGV;
    }
    if (tid == 0) smut[(size_t)b*NB + ii] = NEGV;
    __syncthreads();
  }
}

extern "C" void kernel_launch(void* const* d_in, const int* in_sizes, int n_in,
                              void* d_out, int out_size, void* d_ws, size_t ws_size,
                              hipStream_t stream) {
  const float* scores  = (const float*)d_in[0];
  const float* deltas  = (const float*)d_in[1];
  const float* anchors = (const float*)d_in[2];
  const float* im_info = (const float*)d_in[3];
  const int*   ids     = (const int*)d_in[4];
  float* out = (float*)d_out;

  uint32_t* ctrs = (uint32_t*)d_ws;
  unsigned long long* keys = (unsigned long long*)((char*)d_ws + 64);
  float* smut = (float*)((char*)d_ws + 64 + (size_t)BATCH * MMAX * sizeof(unsigned long long));

  hipLaunchKernelGGL(k_init, dim3(1), dim3(64), 0, stream, ctrs);
  hipLaunchKernelGGL(k_prep, dim3(NB/256, BATCH), dim3(256), 0, stream,
                     scores, deltas, anchors, im_info, ctrs, keys);
  hipLaunchKernelGGL(k_sort, dim3(BATCH), dim3(1024), 0, stream, ctrs, keys);
  hipLaunchKernelGGL(k_nms, dim3(BATCH), dim3(256), 0, stream,
                     deltas, anchors, im_info, ids, ctrs, keys, out);
  hipLaunchKernelGGL(k_fallback, dim3(BATCH), dim3(1024), 0, stream,
                     scores, deltas, anchors, im_info, ids, ctrs, smut, out);
}

// Round 2
// 361.997 us; speedup vs baseline: 1.9754x; 1.9754x over previous
//
#include <hip/hip_runtime.h>
#include <stdint.h>

#define NB     65536
#define BATCH  4
#define TOPN   1000
#define MMAX   2048
#define KSUP   8
#define UNC    128
#define THRESH 0.974f
#define NEGV   (-1e9f)
#define NMS_T  0.7f

// ws layout (bytes):
//   0      : ctrs (12 u32: [0..3]=cand count, [4..7]=max coord bits, [8..11]=fallback flag)
//   256    : cnt      B*MMAX u32  (zeroed by memset together with ctrs)
//   33024  : keys_un  B*MMAX u64
//   98560  : box_un   B*MMAX float4
//   229632 : lev_un   B*MMAX i32
//   262400 : sboxes   B*MMAX float4 (rank-sorted, clipped, non-offset)
//   393472 : slev     B*MMAX i32
//   426240 : suplist  B*MMAX*KSUP i32
#define OFF_CNT     256
#define OFF_KEYS    33024
#define OFF_BOXUN   98560
#define OFF_LEVUN   229632
#define OFF_SBOX    262400
#define OFF_SLEV    393472
#define OFF_SUP     426240

__device__ __forceinline__ void decode_box(const float4* __restrict__ anchors4,
                                           const float4* __restrict__ deltas4,
                                           int b, int i, float wmax, float hmax,
                                           float& x1, float& y1, float& x2, float& y2) {
  float4 a = anchors4[i];
  float4 d = deltas4[(size_t)b * NB + i];
  float ws = a.z - a.x + 1.0f;
  float hs = a.w - a.y + 1.0f;
  float cx = a.x + 0.5f * ws;
  float cy = a.y + 0.5f * hs;
  float pcx = d.x * ws + cx;
  float pcy = d.y * hs + cy;
  float pw = expf(d.z) * ws;
  float ph = expf(d.w) * hs;
  x1 = pcx - 0.5f * pw; y1 = pcy - 0.5f * ph;
  x2 = pcx + 0.5f * pw; y2 = pcy + 0.5f * ph;
  x1 = fminf(fmaxf(x1, 0.0f), wmax);
  y1 = fminf(fmaxf(y1, 0.0f), hmax);
  x2 = fminf(fmaxf(x2, 0.0f), wmax);
  y2 = fminf(fmaxf(y2, 0.0f), hmax);
}

// decode all boxes; wave-reduce coordinate max; emit candidates (score>=THRESH)
__global__ __launch_bounds__(256) void k_prep(const float* __restrict__ scores,
                                              const float4* __restrict__ deltas4,
                                              const float4* __restrict__ anchors4,
                                              const float* __restrict__ im_info,
                                              const int* __restrict__ ids,
                                              uint32_t* ctrs,
                                              unsigned long long* keys,
                                              float4* box_un, int* lev_un) {
  int b = blockIdx.y;
  int i = blockIdx.x * 256 + threadIdx.x;
  float wmax = im_info[b * 3 + 1] - 1.0f;
  float hmax = im_info[b * 3 + 0] - 1.0f;
  float x1, y1, x2, y2;
  decode_box(anchors4, deltas4, b, i, wmax, hmax, x1, y1, x2, y2);
  float m = fmaxf(fmaxf(x1, y1), fmaxf(x2, y2));
  for (int o = 32; o > 0; o >>= 1) m = fmaxf(m, __shfl_xor(m, o, 64));
  if ((threadIdx.x & 63) == 0) atomicMax(&ctrs[4 + b], __float_as_uint(m));
  float sc = scores[(size_t)b * NB + i];
  if (sc >= THRESH) {
    uint32_t slot = atomicAdd(&ctrs[b], 1u);
    if (slot < (uint32_t)MMAX) {
      keys[(size_t)b * MMAX + slot] =
          ((unsigned long long)(~__float_as_uint(sc)) << 32) | (uint32_t)i;
      box_un[(size_t)b * MMAX + slot] = make_float4(x1, y1, x2, y2);
      lev_un[(size_t)b * MMAX + slot] = ids[i];
    } else {
      ctrs[8 + b] = 1u;  // pool overflow -> exact fallback
    }
  }
}

// rank-by-counting sort (keys distinct: idx in low bits); permute boxes/levels
__global__ __launch_bounds__(256) void k_rank(const uint32_t* __restrict__ ctrs,
                                              const unsigned long long* __restrict__ keys,
                                              const float4* __restrict__ box_un,
                                              const int* __restrict__ lev_un,
                                              float4* sboxes, int* slev) {
  int b = blockIdx.y;
  int t = blockIdx.x * 256 + threadIdx.x;
  __shared__ unsigned long long sk[MMAX];
  int n = min((int)ctrs[b], MMAX);
  for (int i = threadIdx.x; i < n; i += 256) sk[i] = keys[(size_t)b * MMAX + i];
  __syncthreads();
  if (t < n) {
    unsigned long long mykey = sk[t];
    int r = 0, i = 0;
    for (; i + 4 <= n; i += 4)
      r += (int)(sk[i] < mykey) + (int)(sk[i+1] < mykey) +
           (int)(sk[i+2] < mykey) + (int)(sk[i+3] < mykey);
    for (; i < n; ++i) r += (int)(sk[i] < mykey);
    sboxes[(size_t)b * MMAX + r] = box_un[(size_t)b * MMAX + t];
    slev[(size_t)b * MMAX + r]   = lev_un[(size_t)b * MMAX + t];
  }
}

// all-pairs potential-suppressor detection (i<j, same level, IoU>0.7 on offset boxes)
__global__ __launch_bounds__(256) void k_pairs(uint32_t* ctrs,
                                               const float4* __restrict__ sboxes,
                                               const int* __restrict__ slev,
                                               uint32_t* cnt, int* suplist) {
  int b = blockIdx.y;
  int blk = blockIdx.x;  // 0..15
  int tid = threadIdx.x;
  __shared__ float4 obox[MMAX];
  __shared__ uint8_t olev[MMAX];
  int n = min((int)ctrs[b], MMAX);
  float max_c = __uint_as_float(ctrs[4 + b]) + 1.0f;
  for (int i = tid; i < n; i += 256) {
    float4 v = sboxes[(size_t)b * MMAX + i];
    int lv = slev[(size_t)b * MMAX + i];
    float off = (float)lv * max_c;
    obox[i] = make_float4(v.x + off, v.y + off, v.z + off, v.w + off);
    olev[i] = (uint8_t)lv;
  }
  __syncthreads();
  int j = blk + ((tid >> 1) << 4);  // stride-16 round robin for balance
  int half = tid & 1;
  if (j < n) {
    float4 J = obox[j];
    int alv = (int)olev[j];
    float aj = (J.z - J.x) * (J.w - J.y);
    for (int i = half; i < j; i += 2) {
      if ((int)olev[i] != alv) continue;
      float4 I = obox[i];
      float xx1 = fmaxf(I.x, J.x), yy1 = fmaxf(I.y, J.y);
      float xx2 = fminf(I.z, J.z), yy2 = fminf(I.w, J.w);
      float inter = fmaxf(xx2 - xx1, 0.0f) * fmaxf(yy2 - yy1, 0.0f);
      float ai = (I.z - I.x) * (I.w - I.y);
      float iou = inter / fmaxf((ai + aj) - inter, 1e-6f);
      if (iou > NMS_T) {
        uint32_t s = atomicAdd(&cnt[(size_t)b * MMAX + j], 1u);
        if (s < (uint32_t)KSUP) suplist[((size_t)b * MMAX + j) * KSUP + s] = i;
        else ctrs[8 + b] = 1u;  // suppressor-list overflow -> fallback
      }
    }
  }
}

// block-wide pair-scan: returns exclusive prefix before this thread's pair; *total_out = grand total
__device__ __forceinline__ uint32_t scan_pair(uint32_t pairsum, volatile uint32_t* wsum,
                                              int tid, uint32_t* total_out) {
  int lane = tid & 63, wid = tid >> 6;
  uint32_t v = pairsum;
  for (int off = 1; off < 64; off <<= 1) {
    uint32_t u = __shfl_up(v, off, 64);
    if (lane >= off) v += u;
  }
  if (lane == 63) wsum[wid] = v;
  __syncthreads();
  if (tid == 0) {
    uint32_t run = 0;
    for (int w = 0; w < 16; ++w) { uint32_t t = wsum[w]; wsum[w] = run; run += t; }
    wsum[16] = run;
  }
  __syncthreads();
  uint32_t incl = v + wsum[wid];
  *total_out = wsum[16];
  return incl - pairsum;
}

// exact ordered resolution of uncertain candidates + compaction + output
__global__ __launch_bounds__(1024) void k_resolve(uint32_t* ctrs,
                                                  const uint32_t* __restrict__ cnt,
                                                  const int* __restrict__ suplist,
                                                  const float4* __restrict__ sboxes,
                                                  float* __restrict__ out) {
  int b = blockIdx.x;
  int tid = threadIdx.x;
  __shared__ uint8_t kept[MMAX];
  __shared__ uint32_t wsum[17];
  __shared__ uint16_t unc[UNC];
  __shared__ int supld[UNC][KSUP];
  __shared__ uint8_t supn[UNC];
  int n = min((int)ctrs[b], MMAX);
  int j0 = tid * 2, j1 = tid * 2 + 1;
  uint32_t c0 = (j0 < n) ? cnt[(size_t)b * MMAX + j0] : 0u;
  uint32_t c1 = (j1 < n) ? cnt[(size_t)b * MMAX + j1] : 0u;
  kept[j0] = (j0 < n && c0 == 0u) ? 1 : 0;
  kept[j1] = (j1 < n && c1 == 0u) ? 1 : 0;
  uint32_t u0 = (j0 < n && c0 > 0u) ? 1u : 0u;
  uint32_t u1 = (j1 < n && c1 > 0u) ? 1u : 0u;
  uint32_t tot_unc;
  uint32_t base = scan_pair(u0 + u1, wsum, tid, &tot_unc);
  if (u0) {
    uint32_t p = base;
    if (p < UNC) {
      int m = (int)min(c0, (uint32_t)KSUP);
      unc[p] = (uint16_t)j0; supn[p] = (uint8_t)m;
      for (int s = 0; s < m; ++s) supld[p][s] = suplist[((size_t)b * MMAX + j0) * KSUP + s];
    }
  }
  if (u1) {
    uint32_t p = base + u0;
    if (p < UNC) {
      int m = (int)min(c1, (uint32_t)KSUP);
      unc[p] = (uint16_t)j1; supn[p] = (uint8_t)m;
      for (int s = 0; s < m; ++s) supld[p][s] = suplist[((size_t)b * MMAX + j1) * KSUP + s];
    }
  }
  __syncthreads();
  if (tid < 64) {  // wave 0: exact greedy resolution in rank order (suppressors have smaller rank)
    int nu = (int)min(tot_unc, (uint32_t)UNC);
    for (int u = 0; u < nu; ++u) {
      int m = (int)supn[u];
      int pred = (tid < m) ? (int)kept[supld[u][tid]] : 0;
      unsigned long long bal = __ballot(pred);
      if (tid == 0) kept[unc[u]] = (bal == 0ULL) ? 1 : 0;
    }
  }
  __syncthreads();
  uint32_t k0 = kept[j0], k1 = kept[j1];
  uint32_t total;
  uint32_t pbase = scan_pair(k0 + k1, wsum, tid, &total);
  if (k0 && pbase < (uint32_t)TOPN) {
    float4 bx = sboxes[(size_t)b * MMAX + j0];
    size_t o = ((size_t)b * TOPN + pbase) * 5;
    out[o] = (float)b; out[o+1] = bx.x; out[o+2] = bx.y; out[o+3] = bx.z; out[o+4] = bx.w;
  }
  if (k1) {
    uint32_t p = pbase + k0;
    if (p < (uint32_t)TOPN) {
      float4 bx = sboxes[(size_t)b * MMAX + j1];
      size_t o = ((size_t)b * TOPN + p) * 5;
      out[o] = (float)b; out[o+1] = bx.x; out[o+2] = bx.y; out[o+3] = bx.z; out[o+4] = bx.w;
    }
  }
  for (int t = tid; t < TOPN; t += 1024) {
    if ((uint32_t)t >= total) {
      size_t o = ((size_t)b * TOPN + t) * 5;
      out[o] = (float)b; out[o+1] = 0.0f; out[o+2] = 0.0f; out[o+3] = 0.0f; out[o+4] = 0.0f;
    }
  }
  if (tid == 0 && (total < (uint32_t)TOPN || tot_unc > (uint32_t)UNC)) ctrs[8 + b] = 1u;
}

// exact brute-force greedy NMS over all 65536; runs only if flag set (expected: never)
__global__ __launch_bounds__(1024) void k_fallback(const float* __restrict__ scores,
                                                   const float4* __restrict__ deltas4,
                                                   const float4* __restrict__ anchors4,
                                                   const float* __restrict__ im_info,
                                                   const int* __restrict__ ids,
                                                   const uint32_t* __restrict__ ctrs,
                                                   float* __restrict__ out) {
  int b = blockIdx.x;
  if (ctrs[8 + b] == 0u) return;
  int tid = threadIdx.x;
  __shared__ uint32_t mask[NB / 32];  // 8 KB suppressed bitmask
  __shared__ float rv[1024];
  __shared__ int ri[1024];
  float max_c = __uint_as_float(ctrs[4 + b]) + 1.0f;
  float wmax = im_info[b * 3 + 1] - 1.0f;
  float hmax = im_info[b * 3 + 0] - 1.0f;
  for (int i = tid; i < NB / 32; i += 1024) mask[i] = 0u;
  __syncthreads();
  for (int it = 0; it < TOPN; ++it) {
    float bv = -3e38f; int bi = 0x7fffffff;
    for (int i = tid; i < NB; i += 1024) {
      bool sup = (mask[i >> 5] >> (i & 31)) & 1u;
      float v = sup ? NEGV : scores[(size_t)b * NB + i];
      if (v > bv || (v == bv && i < bi)) { bv = v; bi = i; }
    }
    rv[tid] = bv; ri[tid] = bi;
    __syncthreads();
    for (int s = 512; s > 0; s >>= 1) {
      if (tid < s) {
        float v2 = rv[tid + s]; int i2 = ri[tid + s];
        if (v2 > rv[tid] || (v2 == rv[tid] && i2 < ri[tid])) { rv[tid] = v2; ri[tid] = i2; }
      }
      __syncthreads();
    }
    int ii = ri[0]; float vv = rv[0];
    bool valid = vv > NEGV * 0.5f;
    if (!valid) {  // everything suppressed: remaining rows are zeros (matches reference)
      if (tid == 0) {
        size_t o = ((size_t)b * TOPN + it) * 5;
        out[o] = (float)b; out[o+1] = 0; out[o+2] = 0; out[o+3] = 0; out[o+4] = 0;
      }
      __syncthreads();
      continue;
    }
    float x1, y1, x2, y2;
    decode_box(anchors4, deltas4, b, ii, wmax, hmax, x1, y1, x2, y2);
    int lv = ids[ii];
    float off = (float)lv * max_c;
    float s0 = x1 + off, s1 = y1 + off, s2 = x2 + off, s3 = y2 + off;
    float a1 = (s2 - s0) * (s3 - s1);
    if (tid == 0) {
      size_t o = ((size_t)b * TOPN + it) * 5;
      out[o] = (float)b; out[o+1] = x1; out[o+2] = y1; out[o+3] = x2; out[o+4] = y2;
    }
    for (int j = tid; j < NB; j += 1024) {
      if ((mask[j >> 5] >> (j & 31)) & 1u) continue;
      if (ids[j] != lv) continue;  // cross-level IoU is exactly 0 (offset geometry)
      float bx1, by1, bx2, by2;
      decode_box(anchors4, deltas4, b, j, wmax, hmax, bx1, by1, bx2, by2);
      float t0 = bx1 + off, t1 = by1 + off, t2 = bx2 + off, t3 = by2 + off;
      float xx1 = fmaxf(s0, t0), yy1 = fmaxf(s1, t1);
      float xx2 = fminf(s2, t2), yy2 = fminf(s3, t3);
      float inter = fmaxf(xx2 - xx1, 0.0f) * fmaxf(yy2 - yy1, 0.0f);
      float a2r = (t2 - t0) * (t3 - t1);
      float iou = inter / fmaxf(a1 + a2r - inter, 1e-6f);
      if (iou > NMS_T) atomicOr(&mask[j >> 5], 1u << (j & 31));
    }
    if (tid == 0) atomicOr(&mask[ii >> 5], 1u << (ii & 31));
    __syncthreads();
  }
}

extern "C" void kernel_launch(void* const* d_in, const int* in_sizes, int n_in,
                              void* d_out, int out_size, void* d_ws, size_t ws_size,
                              hipStream_t stream) {
  const float*  scores   = (const float*)d_in[0];
  const float4* deltas4  = (const float4*)d_in[1];
  const float4* anchors4 = (const float4*)d_in[2];
  const float*  im_info  = (const float*)d_in[3];
  const int*    ids      = (const int*)d_in[4];
  float* out = (float*)d_out;

  char* ws = (char*)d_ws;
  uint32_t*           ctrs    = (uint32_t*)ws;
  uint32_t*           cnt     = (uint32_t*)(ws + OFF_CNT);
  unsigned long long* keys    = (unsigned long long*)(ws + OFF_KEYS);
  float4*             box_un  = (float4*)(ws + OFF_BOXUN);
  int*                lev_un  = (int*)(ws + OFF_LEVUN);
  float4*             sboxes  = (float4*)(ws + OFF_SBOX);
  int*                slev    = (int*)(ws + OFF_SLEV);
  int*                suplist = (int*)(ws + OFF_SUP);

  hipMemsetAsync(d_ws, 0, OFF_CNT + (size_t)BATCH * MMAX * sizeof(uint32_t), stream);
  hipLaunchKernelGGL(k_prep, dim3(NB / 256, BATCH), dim3(256), 0, stream,
                     scores, deltas4, anchors4, im_info, ids, ctrs, keys, box_un, lev_un);
  hipLaunchKernelGGL(k_rank, dim3(MMAX / 256, BATCH), dim3(256), 0, stream,
                     ctrs, keys, box_un, lev_un, sboxes, slev);
  hipLaunchKernelGGL(k_pairs, dim3(16, BATCH), dim3(256), 0, stream,
                     ctrs, sboxes, slev, cnt, suplist);
  hipLaunchKernelGGL(k_resolve, dim3(BATCH), dim3(1024), 0, stream,
                     ctrs, cnt, suplist, sboxes, out);
  hipLaunchKernelGGL(k_fallback, dim3(BATCH), dim3(1024), 0, stream,
                     scores, deltas4, anchors4, im_info, ids, ctrs, out);
}

// Round 3
// 170.677 us; speedup vs baseline: 4.1897x; 2.1209x over previous
//
#include <hip/hip_runtime.h>
#include <stdint.h>

#define NB     65536
#define BATCH  4
#define TOPN   1000
#define MMAX   2048
#define NTILE  (MMAX / 64)            // 32
#define NPAIRS (NTILE * (NTILE + 1) / 2)  // 528
#define KSUP   8
#define UNC    128
#define THRESH 0.974f
#define NEGV   (-1e9f)
#define NMS_T  0.7f

// ws layout (bytes):
//   0      : ctrs (12 u32: [0..3]=cand count, [4..7]=max coord bits, [8..11]=fallback flag)
//   256    : cnt      B*MMAX u32  (zeroed by memset together with ctrs)
//   33024  : keys     B*MMAX u64
//   98560  : box_un   B*MMAX float4
//   229632 : lev_un   B*MMAX i32
//   262400 : sboxes   B*MMAX float4 (rank-sorted, clipped, non-offset)
//   393472 : slev     B*MMAX i32
//   426240 : suplist  B*MMAX*KSUP i32
#define OFF_CNT     256
#define OFF_KEYS    33024
#define OFF_BOXUN   98560
#define OFF_LEVUN   229632
#define OFF_SBOX    262400
#define OFF_SLEV    393472
#define OFF_SUP     426240

__device__ __forceinline__ void decode_box(const float4* __restrict__ anchors4,
                                           const float4* __restrict__ deltas4,
                                           int b, int i, float wmax, float hmax,
                                           float& x1, float& y1, float& x2, float& y2) {
  float4 a = anchors4[i];
  float4 d = deltas4[(size_t)b * NB + i];
  float ws = a.z - a.x + 1.0f;
  float hs = a.w - a.y + 1.0f;
  float cx = a.x + 0.5f * ws;
  float cy = a.y + 0.5f * hs;
  float pcx = d.x * ws + cx;
  float pcy = d.y * hs + cy;
  float pw = expf(d.z) * ws;
  float ph = expf(d.w) * hs;
  x1 = pcx - 0.5f * pw; y1 = pcy - 0.5f * ph;
  x2 = pcx + 0.5f * pw; y2 = pcy + 0.5f * ph;
  x1 = fminf(fmaxf(x1, 0.0f), wmax);
  y1 = fminf(fmaxf(y1, 0.0f), hmax);
  x2 = fminf(fmaxf(x2, 0.0f), wmax);
  y2 = fminf(fmaxf(y2, 0.0f), hmax);
}

// decode all boxes; block-reduce coordinate max (1 atomic/block); emit candidates
__global__ __launch_bounds__(256) void k_prep(const float* __restrict__ scores,
                                              const float4* __restrict__ deltas4,
                                              const float4* __restrict__ anchors4,
                                              const float* __restrict__ im_info,
                                              const int* __restrict__ ids,
                                              uint32_t* ctrs,
                                              unsigned long long* keys,
                                              float4* box_un, int* lev_un) {
  int b = blockIdx.y;
  int i = blockIdx.x * 256 + threadIdx.x;
  float wmax = im_info[b * 3 + 1] - 1.0f;
  float hmax = im_info[b * 3 + 0] - 1.0f;
  float x1, y1, x2, y2;
  decode_box(anchors4, deltas4, b, i, wmax, hmax, x1, y1, x2, y2);
  float m = fmaxf(fmaxf(x1, y1), fmaxf(x2, y2));
  for (int o = 32; o > 0; o >>= 1) m = fmaxf(m, __shfl_xor(m, o, 64));
  __shared__ float bmax[4];
  if ((threadIdx.x & 63) == 0) bmax[threadIdx.x >> 6] = m;
  __syncthreads();
  if (threadIdx.x == 0) {
    float mm = fmaxf(fmaxf(bmax[0], bmax[1]), fmaxf(bmax[2], bmax[3]));
    atomicMax(&ctrs[4 + b], __float_as_uint(mm));  // coords >= 0 -> uint order == float order
  }
  float sc = scores[(size_t)b * NB + i];
  if (sc >= THRESH) {
    uint32_t slot = atomicAdd(&ctrs[b], 1u);
    if (slot < (uint32_t)MMAX) {
      keys[(size_t)b * MMAX + slot] =
          ((unsigned long long)(~__float_as_uint(sc)) << 32) | (uint32_t)i;
      box_un[(size_t)b * MMAX + slot] = make_float4(x1, y1, x2, y2);
      lev_un[(size_t)b * MMAX + slot] = ids[i];
    } else {
      ctrs[8 + b] = 1u;  // pool overflow -> exact fallback
    }
  }
}

// rank-by-counting sort (keys distinct: idx in low bits); permute boxes/levels
__global__ __launch_bounds__(64) void k_rank(const uint32_t* __restrict__ ctrs,
                                             const unsigned long long* __restrict__ keys,
                                             const float4* __restrict__ box_un,
                                             const int* __restrict__ lev_un,
                                             float4* sboxes, int* slev) {
  int b = blockIdx.y;
  int t = blockIdx.x * 64 + threadIdx.x;
  __shared__ unsigned long long sk[MMAX];
  int n = min((int)ctrs[b], MMAX);
  int npad = (n + 7) & ~7;
  for (int i = threadIdx.x; i < npad; i += 64)
    sk[i] = (i < n) ? keys[(size_t)b * MMAX + i] : ~0ULL;
  __syncthreads();
  if (t < n) {
    unsigned long long k = sk[t];
    const ulonglong2* sk2 = (const ulonglong2*)sk;
    int r = 0;
    for (int i = 0; i < (npad >> 1); i += 4) {  // 8 keys / iter, b128 LDS reads
      ulonglong2 a = sk2[i], bb = sk2[i + 1], c = sk2[i + 2], d = sk2[i + 3];
      r += (int)(a.x < k) + (int)(a.y < k) + (int)(bb.x < k) + (int)(bb.y < k) +
           (int)(c.x < k) + (int)(c.y < k) + (int)(d.x < k) + (int)(d.y < k);
    }
    sboxes[(size_t)b * MMAX + r] = box_un[(size_t)b * MMAX + t];
    slev[(size_t)b * MMAX + r]   = lev_un[(size_t)b * MMAX + t];
  }
}

// tiled all-pairs potential-suppressor detection (i<j, same level, IoU>0.7 on offset boxes)
// one wave per 64x64 tile-pair; triangular tile space
__global__ __launch_bounds__(64) void k_pairs(uint32_t* ctrs,
                                              const float4* __restrict__ sboxes,
                                              const int* __restrict__ slev,
                                              uint32_t* cnt, int* suplist) {
  int b = blockIdx.y;
  int p = blockIdx.x;
  int tj = (int)((sqrtf(8.0f * (float)p + 1.0f) - 1.0f) * 0.5f);
  while ((tj + 1) * (tj + 2) / 2 <= p) ++tj;
  while (tj * (tj + 1) / 2 > p) --tj;
  int ti = p - tj * (tj + 1) / 2;
  int n = min((int)ctrs[b], MMAX);
  if (tj * 64 >= n) return;  // uniform across block
  float max_c = __uint_as_float(ctrs[4 + b]) + 1.0f;
  int lane = threadIdx.x;

  __shared__ float4 ib[64];
  __shared__ int il[64];
  int ii = ti * 64 + lane;
  if (ii < n) {
    float4 v = sboxes[(size_t)b * MMAX + ii];
    int lv = slev[(size_t)b * MMAX + ii];
    float off = (float)lv * max_c;
    ib[lane] = make_float4(v.x + off, v.y + off, v.z + off, v.w + off);
    il[lane] = lv;
  } else {
    il[lane] = -1;
  }
  int j = tj * 64 + lane;
  float4 J = make_float4(0.f, 0.f, 0.f, 0.f);
  int jl = -2;
  float aj = 0.0f;
  if (j < n) {
    float4 v = sboxes[(size_t)b * MMAX + j];
    jl = slev[(size_t)b * MMAX + j];
    float off = (float)jl * max_c;
    J = make_float4(v.x + off, v.y + off, v.z + off, v.w + off);
    aj = (J.z - J.x) * (J.w - J.y);
  }
  __syncthreads();
  if (j < n) {
    int imax = (ti == tj) ? lane : 64;  // diagonal: only i<j
    for (int k = 0; k < imax; ++k) {
      if (il[k] != jl) continue;
      float4 I = ib[k];
      float xx1 = fmaxf(I.x, J.x), yy1 = fmaxf(I.y, J.y);
      float xx2 = fminf(I.z, J.z), yy2 = fminf(I.w, J.w);
      float inter = fmaxf(xx2 - xx1, 0.0f) * fmaxf(yy2 - yy1, 0.0f);
      float ai = (I.z - I.x) * (I.w - I.y);
      float iou = inter / fmaxf((ai + aj) - inter, 1e-6f);
      if (iou > NMS_T) {
        uint32_t s = atomicAdd(&cnt[(size_t)b * MMAX + j], 1u);
        if (s < (uint32_t)KSUP) suplist[((size_t)b * MMAX + j) * KSUP + s] = ti * 64 + k;
        else ctrs[8 + b] = 1u;  // suppressor-list overflow -> fallback
      }
    }
  }
}

// block-wide pair-scan: returns exclusive prefix before this thread's pair; *total_out = grand total
__device__ __forceinline__ uint32_t scan_pair(uint32_t pairsum, volatile uint32_t* wsum,
                                              int tid, uint32_t* total_out) {
  int lane = tid & 63, wid = tid >> 6;
  uint32_t v = pairsum;
  for (int off = 1; off < 64; off <<= 1) {
    uint32_t u = __shfl_up(v, off, 64);
    if (lane >= off) v += u;
  }
  if (lane == 63) wsum[wid] = v;
  __syncthreads();
  if (tid == 0) {
    uint32_t run = 0;
    for (int w = 0; w < 16; ++w) { uint32_t t = wsum[w]; wsum[w] = run; run += t; }
    wsum[16] = run;
  }
  __syncthreads();
  uint32_t incl = v + wsum[wid];
  *total_out = wsum[16];
  return incl - pairsum;
}

// exact ordered resolution of uncertain candidates + compaction + output
__global__ __launch_bounds__(1024) void k_resolve(uint32_t* ctrs,
                                                  const uint32_t* __restrict__ cnt,
                                                  const int* __restrict__ suplist,
                                                  const float4* __restrict__ sboxes,
                                                  float* __restrict__ out) {
  int b = blockIdx.x;
  int tid = threadIdx.x;
  __shared__ uint8_t kept[MMAX];
  __shared__ uint32_t wsum[17];
  __shared__ uint16_t unc[UNC];
  __shared__ int supld[UNC][KSUP];
  __shared__ uint8_t supn[UNC];
  int n = min((int)ctrs[b], MMAX);
  int j0 = tid * 2, j1 = tid * 2 + 1;
  uint32_t c0 = (j0 < n) ? cnt[(size_t)b * MMAX + j0] : 0u;
  uint32_t c1 = (j1 < n) ? cnt[(size_t)b * MMAX + j1] : 0u;
  kept[j0] = (j0 < n && c0 == 0u) ? 1 : 0;
  kept[j1] = (j1 < n && c1 == 0u) ? 1 : 0;
  uint32_t u0 = (j0 < n && c0 > 0u) ? 1u : 0u;
  uint32_t u1 = (j1 < n && c1 > 0u) ? 1u : 0u;
  uint32_t tot_unc;
  uint32_t base = scan_pair(u0 + u1, wsum, tid, &tot_unc);
  if (u0) {
    uint32_t p = base;
    if (p < UNC) {
      int m = (int)min(c0, (uint32_t)KSUP);
      unc[p] = (uint16_t)j0; supn[p] = (uint8_t)m;
      for (int s = 0; s < m; ++s) supld[p][s] = suplist[((size_t)b * MMAX + j0) * KSUP + s];
    }
  }
  if (u1) {
    uint32_t p = base + u0;
    if (p < UNC) {
      int m = (int)min(c1, (uint32_t)KSUP);
      unc[p] = (uint16_t)j1; supn[p] = (uint8_t)m;
      for (int s = 0; s < m; ++s) supld[p][s] = suplist[((size_t)b * MMAX + j1) * KSUP + s];
    }
  }
  __syncthreads();
  if (tid < 64) {  // wave 0: exact greedy resolution in rank order (suppressors have smaller rank)
    int nu = (int)min(tot_unc, (uint32_t)UNC);
    for (int u = 0; u < nu; ++u) {
      int m = (int)supn[u];
      int pred = (tid < m) ? (int)kept[supld[u][tid]] : 0;
      unsigned long long bal = __ballot(pred);
      if (tid == 0) kept[unc[u]] = (bal == 0ULL) ? 1 : 0;
    }
  }
  __syncthreads();
  uint32_t k0 = kept[j0], k1 = kept[j1];
  uint32_t total;
  uint32_t pbase = scan_pair(k0 + k1, wsum, tid, &total);
  if (k0 && pbase < (uint32_t)TOPN) {
    float4 bx = sboxes[(size_t)b * MMAX + j0];
    size_t o = ((size_t)b * TOPN + pbase) * 5;
    out[o] = (float)b; out[o+1] = bx.x; out[o+2] = bx.y; out[o+3] = bx.z; out[o+4] = bx.w;
  }
  if (k1) {
    uint32_t p = pbase + k0;
    if (p < (uint32_t)TOPN) {
      float4 bx = sboxes[(size_t)b * MMAX + j1];
      size_t o = ((size_t)b * TOPN + p) * 5;
      out[o] = (float)b; out[o+1] = bx.x; out[o+2] = bx.y; out[o+3] = bx.z; out[o+4] = bx.w;
    }
  }
  for (int t = tid; t < TOPN; t += 1024) {
    if ((uint32_t)t >= total) {
      size_t o = ((size_t)b * TOPN + t) * 5;
      out[o] = (float)b; out[o+1] = 0.0f; out[o+2] = 0.0f; out[o+3] = 0.0f; out[o+4] = 0.0f;
    }
  }
  if (tid == 0 && (total < (uint32_t)TOPN || tot_unc > (uint32_t)UNC)) ctrs[8 + b] = 1u;
}

// exact brute-force greedy NMS over all 65536; runs only if flag set (expected: never)
__global__ __launch_bounds__(1024) void k_fallback(const float* __restrict__ scores,
                                                   const float4* __restrict__ deltas4,
                                                   const float4* __restrict__ anchors4,
                                                   const float* __restrict__ im_info,
                                                   const int* __restrict__ ids,
                                                   const uint32_t* __restrict__ ctrs,
                                                   float* __restrict__ out) {
  int b = blockIdx.x;
  if (ctrs[8 + b] == 0u) return;
  int tid = threadIdx.x;
  __shared__ uint32_t mask[NB / 32];  // 8 KB suppressed bitmask
  __shared__ float rv[1024];
  __shared__ int ri[1024];
  float max_c = __uint_as_float(ctrs[4 + b]) + 1.0f;
  float wmax = im_info[b * 3 + 1] - 1.0f;
  float hmax = im_info[b * 3 + 0] - 1.0f;
  for (int i = tid; i < NB / 32; i += 1024) mask[i] = 0u;
  __syncthreads();
  for (int it = 0; it < TOPN; ++it) {
    float bv = -3e38f; int bi = 0x7fffffff;
    for (int i = tid; i < NB; i += 1024) {
      bool sup = (mask[i >> 5] >> (i & 31)) & 1u;
      float v = sup ? NEGV : scores[(size_t)b * NB + i];
      if (v > bv || (v == bv && i < bi)) { bv = v; bi = i; }
    }
    rv[tid] = bv; ri[tid] = bi;
    __syncthreads();
    for (int s = 512; s > 0; s >>= 1) {
      if (tid < s) {
        float v2 = rv[tid + s]; int i2 = ri[tid + s];
        if (v2 > rv[tid] || (v2 == rv[tid] && i2 < ri[tid])) { rv[tid] = v2; ri[tid] = i2; }
      }
      __syncthreads();
    }
    int ii = ri[0]; float vv = rv[0];
    bool valid = vv > NEGV * 0.5f;
    if (!valid) {
      if (tid == 0) {
        size_t o = ((size_t)b * TOPN + it) * 5;
        out[o] = (float)b; out[o+1] = 0; out[o+2] = 0; out[o+3] = 0; out[o+4] = 0;
      }
      __syncthreads();
      continue;
    }
    float x1, y1, x2, y2;
    decode_box(anchors4, deltas4, b, ii, wmax, hmax, x1, y1, x2, y2);
    int lv = ids[ii];
    float off = (float)lv * max_c;
    float s0 = x1 + off, s1 = y1 + off, s2 = x2 + off, s3 = y2 + off;
    float a1 = (s2 - s0) * (s3 - s1);
    if (tid == 0) {
      size_t o = ((size_t)b * TOPN + it) * 5;
      out[o] = (float)b; out[o+1] = x1; out[o+2] = y1; out[o+3] = x2; out[o+4] = y2;
    }
    for (int j = tid; j < NB; j += 1024) {
      if ((mask[j >> 5] >> (j & 31)) & 1u) continue;
      if (ids[j] != lv) continue;  // cross-level IoU is exactly 0 (offset geometry)
      float bx1, by1, bx2, by2;
      decode_box(anchors4, deltas4, b, j, wmax, hmax, bx1, by1, bx2, by2);
      float t0 = bx1 + off, t1 = by1 + off, t2 = bx2 + off, t3 = by2 + off;
      float xx1 = fmaxf(s0, t0), yy1 = fmaxf(s1, t1);
      float xx2 = fminf(s2, t2), yy2 = fminf(s3, t3);
      float inter = fmaxf(xx2 - xx1, 0.0f) * fmaxf(yy2 - yy1, 0.0f);
      float a2r = (t2 - t0) * (t3 - t1);
      float iou = inter / fmaxf(a1 + a2r - inter, 1e-6f);
      if (iou > NMS_T) atomicOr(&mask[j >> 5], 1u << (j & 31));
    }
    if (tid == 0) atomicOr(&mask[ii >> 5], 1u << (ii & 31));
    __syncthreads();
  }
}

extern "C" void kernel_launch(void* const* d_in, const int* in_sizes, int n_in,
                              void* d_out, int out_size, void* d_ws, size_t ws_size,
                              hipStream_t stream) {
  const float*  scores   = (const float*)d_in[0];
  const float4* deltas4  = (const float4*)d_in[1];
  const float4* anchors4 = (const float4*)d_in[2];
  const float*  im_info  = (const float*)d_in[3];
  const int*    ids      = (const int*)d_in[4];
  float* out = (float*)d_out;

  char* ws = (char*)d_ws;
  uint32_t*           ctrs    = (uint32_t*)ws;
  uint32_t*           cnt     = (uint32_t*)(ws + OFF_CNT);
  unsigned long long* keys    = (unsigned long long*)(ws + OFF_KEYS);
  float4*             box_un  = (float4*)(ws + OFF_BOXUN);
  int*                lev_un  = (int*)(ws + OFF_LEVUN);
  float4*             sboxes  = (float4*)(ws + OFF_SBOX);
  int*                slev    = (int*)(ws + OFF_SLEV);
  int*                suplist = (int*)(ws + OFF_SUP);

  hipMemsetAsync(d_ws, 0, OFF_CNT + (size_t)BATCH * MMAX * sizeof(uint32_t), stream);
  hipLaunchKernelGGL(k_prep, dim3(NB / 256, BATCH), dim3(256), 0, stream,
                     scores, deltas4, anchors4, im_info, ids, ctrs, keys, box_un, lev_un);
  hipLaunchKernelGGL(k_rank, dim3(MMAX / 64, BATCH), dim3(64), 0, stream,
                     ctrs, keys, box_un, lev_un, sboxes, slev);
  hipLaunchKernelGGL(k_pairs, dim3(NPAIRS, BATCH), dim3(64), 0, stream,
                     ctrs, sboxes, slev, cnt, suplist);
  hipLaunchKernelGGL(k_resolve, dim3(BATCH), dim3(1024), 0, stream,
                     ctrs, cnt, suplist, sboxes, out);
  hipLaunchKernelGGL(k_fallback, dim3(BATCH), dim3(1024), 0, stream,
                     scores, deltas4, anchors4, im_info, ids, ctrs, out);
}

// Round 5
// 102.662 us; speedup vs baseline: 6.9654x; 1.6625x over previous
//
#include <hip/hip_runtime.h>
#include <stdint.h>

#define NB     65536
#define BATCH  4
#define TOPN   1000
#define MMAX   2048
#define NTILE  (MMAX / 64)                 // 32
#define NPAIRS (NTILE * (NTILE + 1) / 2)   // 528
#define CAP    128                         // per-prep-block candidate region
#define KSUP   8
#define UNC    128
#define THRESH 0.974f
#define NEGV   (-1e9f)
#define NMS_T  0.7f

// ws layout (bytes):
//   0      : ctrs u32[16] ([0..3]=n, [4..7]=max coord bits, [8..11]=fallback flag)
//   64     : cnt_blk  u32[256]   per prep-block true candidate count
//   1088   : maxc_blk u32[256]   per prep-block max coord (float bits, >=0)
//   2112   : keys_raw u64[256*CAP]
//   264256 : sboxes   float4[B*MMAX]  rank-sorted, clipped, non-offset
//   395328 : slev     i32[B*MMAX]
//   428096 : cnt2     u32[B*MMAX]     per-candidate suppressor counts (zeroed by k_rank)
//   460864 : suplist  i32[B*MMAX*KSUP]
#define OFF_CBLK   64
#define OFF_MBLK   1088
#define OFF_KRAW   2112
#define OFF_SBOX   264256
#define OFF_SLEV   395328
#define OFF_CNT2   428096
#define OFF_SUP    460864

__device__ __forceinline__ void decode_box(const float4* __restrict__ anchors4,
                                           const float4* __restrict__ deltas4,
                                           int b, int i, float wmax, float hmax,
                                           float& x1, float& y1, float& x2, float& y2) {
  float4 a = anchors4[i];
  float4 d = deltas4[(size_t)b * NB + i];
  float ws = a.z - a.x + 1.0f;
  float hs = a.w - a.y + 1.0f;
  float cx = a.x + 0.5f * ws;
  float cy = a.y + 0.5f * hs;
  float pcx = d.x * ws + cx;
  float pcy = d.y * hs + cy;
  float pw = expf(d.z) * ws;
  float ph = expf(d.w) * hs;
  x1 = pcx - 0.5f * pw; y1 = pcy - 0.5f * ph;
  x2 = pcx + 0.5f * pw; y2 = pcy + 0.5f * ph;
  x1 = fminf(fmaxf(x1, 0.0f), wmax);
  y1 = fminf(fmaxf(y1, 0.0f), hmax);
  x2 = fminf(fmaxf(x2, 0.0f), wmax);
  y2 = fminf(fmaxf(y2, 0.0f), hmax);
}

// block-wide exclusive scan, 256 threads (4 waves). wsum: u32[5].
__device__ __forceinline__ uint32_t blockscan(uint32_t v, volatile uint32_t* wsum,
                                              int tid, uint32_t* total) {
  __syncthreads();
  int lane = tid & 63, wid = tid >> 6;
  uint32_t x = v;
  for (int off = 1; off < 64; off <<= 1) {
    uint32_t u = __shfl_up(x, off, 64);
    if (lane >= off) x += u;
  }
  if (lane == 63) wsum[wid] = x;
  __syncthreads();
  if (tid == 0) {
    uint32_t run = 0;
    for (int w = 0; w < 4; ++w) { uint32_t t = wsum[w]; wsum[w] = run; run += t; }
    wsum[4] = run;
  }
  __syncthreads();
  *total = wsum[4];
  return x - v + wsum[wid];
}

// decode all boxes; per-block max + candidate emission into PRIVATE region (no atomics)
__global__ __launch_bounds__(256) void k_prep(const float* __restrict__ scores,
                                              const float4* __restrict__ deltas4,
                                              const float4* __restrict__ anchors4,
                                              const float* __restrict__ im_info,
                                              unsigned long long* __restrict__ keys_raw,
                                              uint32_t* __restrict__ cnt_blk,
                                              uint32_t* __restrict__ maxc_blk) {
  const int b = blockIdx.x >> 6;       // 64 blocks / image
  const int blk = blockIdx.x & 63;     // 1024 elems / block
  const int tid = threadIdx.x;
  const int lane = tid & 63, wid = tid >> 6;
  __shared__ uint32_t wsum[5];
  __shared__ float fred[4];
  const float wmax = im_info[b * 3 + 1] - 1.0f;
  const float hmax = im_info[b * 3 + 0] - 1.0f;
  float sc4[4];
  uint32_t cmask = 0, ccount = 0;
  float mcoord = 0.0f;
#pragma unroll
  for (int k = 0; k < 4; ++k) {
    int i = (blk << 10) + (k << 8) + tid;
    float x1, y1, x2, y2;
    decode_box(anchors4, deltas4, b, i, wmax, hmax, x1, y1, x2, y2);
    mcoord = fmaxf(mcoord, fmaxf(fmaxf(x1, y1), fmaxf(x2, y2)));
    float sc = scores[(size_t)b * NB + i];
    sc4[k] = sc;
    if (sc >= THRESH) { cmask |= (1u << k); ccount++; }
  }
  for (int o = 32; o > 0; o >>= 1) mcoord = fmaxf(mcoord, __shfl_xor(mcoord, o, 64));
  if (lane == 0) fred[wid] = mcoord;
  uint32_t total;
  uint32_t ebase = blockscan(ccount, wsum, tid, &total);  // internal syncs make fred visible
  if (tid == 0) {
    cnt_blk[blockIdx.x] = total;  // TRUE count (k_rank detects >CAP)
    maxc_blk[blockIdx.x] =
        __float_as_uint(fmaxf(fmaxf(fred[0], fred[1]), fmaxf(fred[2], fred[3])));
  }
  uint32_t p = ebase;
  unsigned long long* dst = keys_raw + (size_t)blockIdx.x * CAP;
#pragma unroll
  for (int k = 0; k < 4; ++k) {
    if (cmask & (1u << k)) {
      if (p < (uint32_t)CAP) {
        int i = (blk << 10) + (k << 8) + tid;
        dst[p] = ((unsigned long long)(~__float_as_uint(sc4[k])) << 32) | (uint32_t)i;
      }
      p++;
    }
  }
}

// gather per-block counts -> bases; compact keys to LDS; rank-by-counting (broadcast
// windows); decode+write sorted boxes/levels; publish ctrs; zero cnt2.
__global__ __launch_bounds__(256) void k_rank(const uint32_t* __restrict__ cnt_blk,
                                              const uint32_t* __restrict__ maxc_blk,
                                              const unsigned long long* __restrict__ keys_raw,
                                              const float4* __restrict__ deltas4,
                                              const float4* __restrict__ anchors4,
                                              const float* __restrict__ im_info,
                                              const int* __restrict__ ids,
                                              uint32_t* ctrs,
                                              float4* sboxes, int* slev,
                                              uint32_t* cnt2) {
  const int b = blockIdx.y;
  const int r = blockIdx.x;            // 0..31: owns candidates [r*64, r*64+64)
  const int tid = threadIdx.x;
  const int lane = tid & 63, wid = tid >> 6;
  __shared__ unsigned long long sk[MMAX];   // 16 KB
  __shared__ uint32_t scnt[64], sbs[64];
  __shared__ uint32_t psum[256];
  __shared__ uint32_t meta[3];              // [0]=n_capped_sum [1]=maxbits [2]=ovflag

  if (tid < 64) {
    uint32_t c = cnt_blk[b * 64 + tid];
    uint32_t cc = min(c, (uint32_t)CAP);
    uint32_t mb = maxc_blk[b * 64 + tid];
    scnt[tid] = cc;
    uint32_t x = cc;
    for (int off = 1; off < 64; off <<= 1) {
      uint32_t u = __shfl_up(x, off, 64);
      if (lane >= off) x += u;
    }
    sbs[tid] = x - cc;
    for (int off = 32; off > 0; off >>= 1)
      mb = max(mb, (uint32_t)__shfl_xor((int)mb, off, 64));  // coords>=0: uint order==float
    unsigned long long ov = __ballot(c > (uint32_t)CAP);
    if (tid == 63) { meta[0] = x; meta[2] = (ov != 0ULL) ? 1u : 0u; }
    if (tid == 0) meta[1] = mb;
  }
  __syncthreads();
  uint32_t nsum = meta[0];
  int n = min((int)nsum, MMAX);
  uint32_t flag = meta[2] | ((nsum > (uint32_t)MMAX) ? 1u : 0u);
  if (r == 0 && tid == 0) {
    ctrs[b] = (uint32_t)n;
    ctrs[4 + b] = meta[1];
    ctrs[8 + b] = flag;
  }
  if (tid < 64) cnt2[(size_t)b * MMAX + r * 64 + tid] = 0u;  // 32 blocks x 64 = MMAX
  // compact: thread group of 4 per source block
  {
    int k = tid >> 2, q = tid & 3;
    uint32_t cb = sbs[k], cc = scnt[k];
    const unsigned long long* src = keys_raw + ((size_t)b * 64 + k) * CAP;
    for (uint32_t o = q; o < cc; o += 4) {
      uint32_t d = cb + o;
      if (d < (uint32_t)MMAX) sk[d] = src[o];
    }
  }
  for (int i = tid; i < MMAX; i += 256) if (i >= n) sk[i] = ~0ULL;
  __syncthreads();
  // rank my 64 candidates: each wave counts one 512-key window (broadcast reads)
  int c = r * 64 + lane;
  uint32_t partial = 0;
  if (c < n) {
    unsigned long long myk = sk[c];
    const ulonglong2* p2 = (const ulonglong2*)(sk + (size_t)wid * 512);
    for (int it = 0; it < 256; it += 4) {
      ulonglong2 a = p2[it], bq = p2[it + 1], cq = p2[it + 2], dq = p2[it + 3];
      partial += (uint32_t)(a.x < myk) + (uint32_t)(a.y < myk) +
                 (uint32_t)(bq.x < myk) + (uint32_t)(bq.y < myk) +
                 (uint32_t)(cq.x < myk) + (uint32_t)(cq.y < myk) +
                 (uint32_t)(dq.x < myk) + (uint32_t)(dq.y < myk);
    }
  }
  psum[wid * 64 + lane] = partial;
  __syncthreads();
  if (tid < 64) {
    int cc = r * 64 + tid;
    if (cc < n) {
      uint32_t rank = psum[tid] + psum[64 + tid] + psum[128 + tid] + psum[192 + tid];
      if (rank < (uint32_t)MMAX) {
        unsigned long long key = sk[cc];
        int i = (int)(uint32_t)key;
        float wmax = im_info[b * 3 + 1] - 1.0f;
        float hmax = im_info[b * 3 + 0] - 1.0f;
        float x1, y1, x2, y2;
        decode_box(anchors4, deltas4, b, i, wmax, hmax, x1, y1, x2, y2);
        sboxes[(size_t)b * MMAX + rank] = make_float4(x1, y1, x2, y2);
        slev[(size_t)b * MMAX + rank] = ids[i];
      }
    }
  }
}

// tiled all-pairs potential-suppressor detection (verbatim round-3, passed)
__global__ __launch_bounds__(64) void k_pairs(uint32_t* ctrs,
                                              const float4* __restrict__ sboxes,
                                              const int* __restrict__ slev,
                                              uint32_t* cnt2, int* suplist) {
  int b = blockIdx.y;
  int p = blockIdx.x;
  int tj = (int)((sqrtf(8.0f * (float)p + 1.0f) - 1.0f) * 0.5f);
  while ((tj + 1) * (tj + 2) / 2 <= p) ++tj;
  while (tj * (tj + 1) / 2 > p) --tj;
  int ti = p - tj * (tj + 1) / 2;
  int n = min((int)ctrs[b], MMAX);
  if (tj * 64 >= n) return;  // uniform across block
  float max_c = __uint_as_float(ctrs[4 + b]) + 1.0f;
  int lane = threadIdx.x;

  __shared__ float4 ib[64];
  __shared__ int il[64];
  int ii = ti * 64 + lane;
  if (ii < n) {
    float4 v = sboxes[(size_t)b * MMAX + ii];
    int lv = slev[(size_t)b * MMAX + ii];
    float off = (float)lv * max_c;
    ib[lane] = make_float4(v.x + off, v.y + off, v.z + off, v.w + off);
    il[lane] = lv;
  } else {
    il[lane] = -1;
  }
  int j = tj * 64 + lane;
  float4 J = make_float4(0.f, 0.f, 0.f, 0.f);
  int jl = -2;
  float aj = 0.0f;
  if (j < n) {
    float4 v = sboxes[(size_t)b * MMAX + j];
    jl = slev[(size_t)b * MMAX + j];
    float off = (float)jl * max_c;
    J = make_float4(v.x + off, v.y + off, v.z + off, v.w + off);
    aj = (J.z - J.x) * (J.w - J.y);
  }
  __syncthreads();
  if (j < n) {
    int imax = (ti == tj) ? lane : 64;  // diagonal: only i<j
    for (int k = 0; k < imax; ++k) {
      if (il[k] != jl) continue;
      float4 I = ib[k];
      float xx1 = fmaxf(I.x, J.x), yy1 = fmaxf(I.y, J.y);
      float xx2 = fminf(I.z, J.z), yy2 = fminf(I.w, J.w);
      float inter = fmaxf(xx2 - xx1, 0.0f) * fmaxf(yy2 - yy1, 0.0f);
      float ai = (I.z - I.x) * (I.w - I.y);
      float iou = inter / fmaxf((ai + aj) - inter, 1e-6f);
      if (iou > NMS_T) {
        uint32_t s = atomicAdd(&cnt2[(size_t)b * MMAX + j], 1u);
        if (s < (uint32_t)KSUP) suplist[((size_t)b * MMAX + j) * KSUP + s] = ti * 64 + k;
        else ctrs[8 + b] = 1u;  // suppressor-list overflow -> fallback
      }
    }
  }
}

// 1024-thread (16-wave) scan for k_resolve (verbatim round-3, passed)
__device__ __forceinline__ uint32_t scan_pair(uint32_t pairsum, volatile uint32_t* wsum,
                                              int tid, uint32_t* total_out) {
  int lane = tid & 63, wid = tid >> 6;
  uint32_t v = pairsum;
  for (int off = 1; off < 64; off <<= 1) {
    uint32_t u = __shfl_up(v, off, 64);
    if (lane >= off) v += u;
  }
  if (lane == 63) wsum[wid] = v;
  __syncthreads();
  if (tid == 0) {
    uint32_t run = 0;
    for (int w = 0; w < 16; ++w) { uint32_t t = wsum[w]; wsum[w] = run; run += t; }
    wsum[16] = run;
  }
  __syncthreads();
  uint32_t incl = v + wsum[wid];
  *total_out = wsum[16];
  return incl - pairsum;
}

// exact ordered resolution + compaction + output (verbatim round-3, passed)
__global__ __launch_bounds__(1024) void k_resolve(uint32_t* ctrs,
                                                  const uint32_t* __restrict__ cnt2,
                                                  const int* __restrict__ suplist,
                                                  const float4* __restrict__ sboxes,
                                                  float* __restrict__ out) {
  int b = blockIdx.x;
  int tid = threadIdx.x;
  __shared__ uint8_t kept[MMAX];
  __shared__ uint32_t wsum[17];
  __shared__ uint16_t unc[UNC];
  __shared__ int supld[UNC][KSUP];
  __shared__ uint8_t supn[UNC];
  int n = min((int)ctrs[b], MMAX);
  int j0 = tid * 2, j1 = tid * 2 + 1;
  uint32_t c0 = (j0 < n) ? cnt2[(size_t)b * MMAX + j0] : 0u;
  uint32_t c1 = (j1 < n) ? cnt2[(size_t)b * MMAX + j1] : 0u;
  kept[j0] = (j0 < n && c0 == 0u) ? 1 : 0;
  kept[j1] = (j1 < n && c1 == 0u) ? 1 : 0;
  uint32_t u0 = (j0 < n && c0 > 0u) ? 1u : 0u;
  uint32_t u1 = (j1 < n && c1 > 0u) ? 1u : 0u;
  uint32_t tot_unc;
  uint32_t base = scan_pair(u0 + u1, wsum, tid, &tot_unc);
  if (u0) {
    uint32_t p = base;
    if (p < UNC) {
      int m = (int)min(c0, (uint32_t)KSUP);
      unc[p] = (uint16_t)j0; supn[p] = (uint8_t)m;
      for (int s = 0; s < m; ++s) supld[p][s] = suplist[((size_t)b * MMAX + j0) * KSUP + s];
    }
  }
  if (u1) {
    uint32_t p = base + u0;
    if (p < UNC) {
      int m = (int)min(c1, (uint32_t)KSUP);
      unc[p] = (uint16_t)j1; supn[p] = (uint8_t)m;
      for (int s = 0; s < m; ++s) supld[p][s] = suplist[((size_t)b * MMAX + j1) * KSUP + s];
    }
  }
  __syncthreads();
  if (tid < 64) {  // wave 0: exact greedy resolution in ascending rank order
    int nu = (int)min(tot_unc, (uint32_t)UNC);
    for (int u = 0; u < nu; ++u) {
      int m = (int)supn[u];
      int pred = (tid < m) ? (int)kept[supld[u][tid]] : 0;
      unsigned long long bal = __ballot(pred);
      if (tid == 0) kept[unc[u]] = (bal == 0ULL) ? 1 : 0;
    }
  }
  __syncthreads();
  uint32_t k0 = kept[j0], k1 = kept[j1];
  uint32_t total;
  uint32_t pbase = scan_pair(k0 + k1, wsum, tid, &total);
  if (k0 && pbase < (uint32_t)TOPN) {
    float4 bx = sboxes[(size_t)b * MMAX + j0];
    size_t o = ((size_t)b * TOPN + pbase) * 5;
    out[o] = (float)b; out[o+1] = bx.x; out[o+2] = bx.y; out[o+3] = bx.z; out[o+4] = bx.w;
  }
  if (k1) {
    uint32_t p = pbase + k0;
    if (p < (uint32_t)TOPN) {
      float4 bx = sboxes[(size_t)b * MMAX + j1];
      size_t o = ((size_t)b * TOPN + p) * 5;
      out[o] = (float)b; out[o+1] = bx.x; out[o+2] = bx.y; out[o+3] = bx.z; out[o+4] = bx.w;
    }
  }
  for (int t = tid; t < TOPN; t += 1024) {
    if ((uint32_t)t >= total) {
      size_t o = ((size_t)b * TOPN + t) * 5;
      out[o] = (float)b; out[o+1] = 0.0f; out[o+2] = 0.0f; out[o+3] = 0.0f; out[o+4] = 0.0f;
    }
  }
  if (tid == 0 && (total < (uint32_t)TOPN || tot_unc > (uint32_t)UNC)) ctrs[8 + b] = 1u;
}

// exact brute-force greedy NMS over all 65536; runs only if flag set (expected: never)
__global__ __launch_bounds__(1024) void k_fallback(const float* __restrict__ scores,
                                                   const float4* __restrict__ deltas4,
                                                   const float4* __restrict__ anchors4,
                                                   const float* __restrict__ im_info,
                                                   const int* __restrict__ ids,
                                                   const uint32_t* __restrict__ ctrs,
                                                   float* __restrict__ out) {
  int b = blockIdx.x;
  if (ctrs[8 + b] == 0u) return;
  int tid = threadIdx.x;
  __shared__ uint32_t mask[NB / 32];
  __shared__ float rv[1024];
  __shared__ int ri[1024];
  float max_c = __uint_as_float(ctrs[4 + b]) + 1.0f;
  float wmax = im_info[b * 3 + 1] - 1.0f;
  float hmax = im_info[b * 3 + 0] - 1.0f;
  for (int i = tid; i < NB / 32; i += 1024) mask[i] = 0u;
  __syncthreads();
  for (int it = 0; it < TOPN; ++it) {
    float bv = -3e38f; int bi = 0x7fffffff;
    for (int i = tid; i < NB; i += 1024) {
      bool sup = (mask[i >> 5] >> (i & 31)) & 1u;
      float v = sup ? NEGV : scores[(size_t)b * NB + i];
      if (v > bv || (v == bv && i < bi)) { bv = v; bi = i; }
    }
    rv[tid] = bv; ri[tid] = bi;
    __syncthreads();
    for (int s = 512; s > 0; s >>= 1) {
      if (tid < s) {
        float v2 = rv[tid + s]; int i2 = ri[tid + s];
        if (v2 > rv[tid] || (v2 == rv[tid] && i2 < ri[tid])) { rv[tid] = v2; ri[tid] = i2; }
      }
      __syncthreads();
    }
    int ii = ri[0]; float vv = rv[0];
    bool valid = vv > NEGV * 0.5f;
    if (!valid) {
      if (tid == 0) {
        size_t o = ((size_t)b * TOPN + it) * 5;
        out[o] = (float)b; out[o+1] = 0; out[o+2] = 0; out[o+3] = 0; out[o+4] = 0;
      }
      __syncthreads();
      continue;
    }
    float x1, y1, x2, y2;
    decode_box(anchors4, deltas4, b, ii, wmax, hmax, x1, y1, x2, y2);
    int lv = ids[ii];
    float off = (float)lv * max_c;
    float s0 = x1 + off, s1 = y1 + off, s2 = x2 + off, s3 = y2 + off;
    float a1 = (s2 - s0) * (s3 - s1);
    if (tid == 0) {
      size_t o = ((size_t)b * TOPN + it) * 5;
      out[o] = (float)b; out[o+1] = x1; out[o+2] = y1; out[o+3] = x2; out[o+4] = y2;
    }
    for (int j = tid; j < NB; j += 1024) {
      if ((mask[j >> 5] >> (j & 31)) & 1u) continue;
      if (ids[j] != lv) continue;  // cross-level IoU is exactly 0 (offset geometry)
      float bx1, by1, bx2, by2;
      decode_box(anchors4, deltas4, b, j, wmax, hmax, bx1, by1, bx2, by2);
      float t0 = bx1 + off, t1 = by1 + off, t2 = bx2 + off, t3 = by2 + off;
      float xx1 = fmaxf(s0, t0), yy1 = fmaxf(s1, t1);
      float xx2 = fminf(s2, t2), yy2 = fminf(s3, t3);
      float inter = fmaxf(xx2 - xx1, 0.0f) * fmaxf(yy2 - yy1, 0.0f);
      float a2r = (t2 - t0) * (t3 - t1);
      float iou = inter / fmaxf(a1 + a2r - inter, 1e-6f);
      if (iou > NMS_T) atomicOr(&mask[j >> 5], 1u << (j & 31));
    }
    if (tid == 0) atomicOr(&mask[ii >> 5], 1u << (ii & 31));
    __syncthreads();
  }
}

extern "C" void kernel_launch(void* const* d_in, const int* in_sizes, int n_in,
                              void* d_out, int out_size, void* d_ws, size_t ws_size,
                              hipStream_t stream) {
  const float*  scores   = (const float*)d_in[0];
  const float4* deltas4  = (const float4*)d_in[1];
  const float4* anchors4 = (const float4*)d_in[2];
  const float*  im_info  = (const float*)d_in[3];
  const int*    ids      = (const int*)d_in[4];
  float* out = (float*)d_out;

  char* ws = (char*)d_ws;
  uint32_t*           ctrs     = (uint32_t*)ws;
  uint32_t*           cnt_blk  = (uint32_t*)(ws + OFF_CBLK);
  uint32_t*           maxc_blk = (uint32_t*)(ws + OFF_MBLK);
  unsigned long long* keys_raw = (unsigned long long*)(ws + OFF_KRAW);
  float4*             sboxes   = (float4*)(ws + OFF_SBOX);
  int*                slev     = (int*)(ws + OFF_SLEV);
  uint32_t*           cnt2     = (uint32_t*)(ws + OFF_CNT2);
  int*                suplist  = (int*)(ws + OFF_SUP);

  hipLaunchKernelGGL(k_prep, dim3(64 * BATCH), dim3(256), 0, stream,
                     scores, deltas4, anchors4, im_info, keys_raw, cnt_blk, maxc_blk);
  hipLaunchKernelGGL(k_rank, dim3(NTILE, BATCH), dim3(256), 0, stream,
                     cnt_blk, maxc_blk, keys_raw, deltas4, anchors4, im_info, ids,
                     ctrs, sboxes, slev, cnt2);
  hipLaunchKernelGGL(k_pairs, dim3(NPAIRS, BATCH), dim3(64), 0, stream,
                     ctrs, sboxes, slev, cnt2, suplist);
  hipLaunchKernelGGL(k_resolve, dim3(BATCH), dim3(1024), 0, stream,
                     ctrs, cnt2, suplist, sboxes, out);
  hipLaunchKernelGGL(k_fallback, dim3(BATCH), dim3(1024), 0, stream,
                     scores, deltas4, anchors4, im_info, ids, ctrs, out);
}

// Round 6
// 101.697 us; speedup vs baseline: 7.0315x; 1.0095x over previous
//
#include <hip/hip_runtime.h>
#include <stdint.h>

#define NB     65536
#define BATCH  4
#define TOPN   1000
#define MMAX   2048
#define NTILE  (MMAX / 64)                 // 32
#define NPAIRS (NTILE * (NTILE + 1) / 2)   // 528
#define CAP    128                         // per-prep-block candidate region
#define KSUP   8
#define UNC    128
#define THRESH 0.974f
#define NEGV   (-1e9f)
#define NMS_T  0.7f

// ws layout (bytes):
//   0      : ctrs u32[16] ([0..3]=n, [8..11]=fallback flag)
//   64     : cnt_blk  u32[256]   per prep-block true candidate count
//   1088   : keys_raw u64[256*CAP]
//   263232 : sboxes   float4[B*MMAX]  rank-sorted, clipped, non-offset
//   394304 : slev     i32[B*MMAX]
//   427072 : cnt2     u32[B*MMAX]  per-candidate suppressor counts (zeroed by k_rank)
//   459840 : suplist  i32[B*MMAX*KSUP]
#define OFF_CBLK   64
#define OFF_KRAW   1088
#define OFF_SBOX   263232
#define OFF_SLEV   394304
#define OFF_CNT2   427072
#define OFF_SUP    459840

__device__ __forceinline__ void decode_box(const float4* __restrict__ anchors4,
                                           const float4* __restrict__ deltas4,
                                           int b, int i, float wmax, float hmax,
                                           float& x1, float& y1, float& x2, float& y2) {
  float4 a = anchors4[i];
  float4 d = deltas4[(size_t)b * NB + i];
  float ws = a.z - a.x + 1.0f;
  float hs = a.w - a.y + 1.0f;
  float cx = a.x + 0.5f * ws;
  float cy = a.y + 0.5f * hs;
  float pcx = d.x * ws + cx;
  float pcy = d.y * hs + cy;
  float pw = expf(d.z) * ws;
  float ph = expf(d.w) * hs;
  x1 = pcx - 0.5f * pw; y1 = pcy - 0.5f * ph;
  x2 = pcx + 0.5f * pw; y2 = pcy + 0.5f * ph;
  x1 = fminf(fmaxf(x1, 0.0f), wmax);
  y1 = fminf(fmaxf(y1, 0.0f), hmax);
  x2 = fminf(fmaxf(x2, 0.0f), wmax);
  y2 = fminf(fmaxf(y2, 0.0f), hmax);
}

// block-wide exclusive scan, 256 threads (4 waves). wsum: u32[5].
__device__ __forceinline__ uint32_t blockscan(uint32_t v, volatile uint32_t* wsum,
                                              int tid, uint32_t* total) {
  __syncthreads();
  int lane = tid & 63, wid = tid >> 6;
  uint32_t x = v;
  for (int off = 1; off < 64; off <<= 1) {
    uint32_t u = __shfl_up(x, off, 64);
    if (lane >= off) x += u;
  }
  if (lane == 63) wsum[wid] = x;
  __syncthreads();
  if (tid == 0) {
    uint32_t run = 0;
    for (int w = 0; w < 4; ++w) { uint32_t t = wsum[w]; wsum[w] = run; run += t; }
    wsum[4] = run;
  }
  __syncthreads();
  *total = wsum[4];
  return x - v + wsum[wid];
}

// pure score-threshold scan: float4 loads, per-block private emission (no decode, no atomics)
__global__ __launch_bounds__(256) void k_prep(const float* __restrict__ scores,
                                              unsigned long long* __restrict__ keys_raw,
                                              uint32_t* __restrict__ cnt_blk) {
  const int b = blockIdx.x >> 6;       // 64 blocks / image
  const int blk = blockIdx.x & 63;     // 1024 scores / block
  const int tid = threadIdx.x;
  __shared__ uint32_t wsum[5];
  const float4* s4 = (const float4*)scores + (size_t)b * (NB / 4) + (size_t)blk * 256 + tid;
  float4 s = *s4;
  float sc4[4] = {s.x, s.y, s.z, s.w};
  uint32_t cmask = 0, ccount = 0;
#pragma unroll
  for (int k = 0; k < 4; ++k)
    if (sc4[k] >= THRESH) { cmask |= (1u << k); ccount++; }
  uint32_t total;
  uint32_t p = blockscan(ccount, wsum, tid, &total);
  if (tid == 0) cnt_blk[blockIdx.x] = total;  // TRUE count (k_rank detects >CAP)
  unsigned long long* dst = keys_raw + (size_t)blockIdx.x * CAP;
#pragma unroll
  for (int k = 0; k < 4; ++k) {
    if (cmask & (1u << k)) {
      if (p < (uint32_t)CAP) {
        int i = (blk << 10) + (tid << 2) + k;
        dst[p] = ((unsigned long long)(~__float_as_uint(sc4[k])) << 32) | (uint32_t)i;
      }
      p++;
    }
  }
}

// gather per-block counts -> bases; compact keys to LDS; rank-by-counting (broadcast
// windows); decode+write sorted boxes/levels; publish ctrs; zero cnt2.
__global__ __launch_bounds__(256) void k_rank(const uint32_t* __restrict__ cnt_blk,
                                              const unsigned long long* __restrict__ keys_raw,
                                              const float4* __restrict__ deltas4,
                                              const float4* __restrict__ anchors4,
                                              const float* __restrict__ im_info,
                                              const int* __restrict__ ids,
                                              uint32_t* ctrs,
                                              float4* sboxes, int* slev,
                                              uint32_t* cnt2) {
  const int b = blockIdx.y;
  const int r = blockIdx.x;            // 0..31: owns candidates [r*64, r*64+64)
  const int tid = threadIdx.x;
  const int lane = tid & 63, wid = tid >> 6;
  __shared__ unsigned long long sk[MMAX];   // 16 KB
  __shared__ uint32_t scnt[64], sbs[64];
  __shared__ uint32_t psum[256];
  __shared__ uint32_t meta[2];              // [0]=n_capped_sum [1]=ovflag

  if (tid < 64) {
    uint32_t c = cnt_blk[b * 64 + tid];
    uint32_t cc = min(c, (uint32_t)CAP);
    scnt[tid] = cc;
    uint32_t x = cc;
    for (int off = 1; off < 64; off <<= 1) {
      uint32_t u = __shfl_up(x, off, 64);
      if (lane >= off) x += u;
    }
    sbs[tid] = x - cc;
    unsigned long long ov = __ballot(c > (uint32_t)CAP);
    if (tid == 63) { meta[0] = x; meta[1] = (ov != 0ULL) ? 1u : 0u; }
  }
  __syncthreads();
  uint32_t nsum = meta[0];
  int n = min((int)nsum, MMAX);
  uint32_t flag = meta[1] | ((nsum > (uint32_t)MMAX) ? 1u : 0u);
  if (r == 0 && tid == 0) {
    ctrs[b] = (uint32_t)n;
    ctrs[8 + b] = flag;
  }
  if (tid < 64) cnt2[(size_t)b * MMAX + r * 64 + tid] = 0u;  // 32 blocks x 64 = MMAX
  // compact: thread group of 4 per source block
  {
    int k = tid >> 2, q = tid & 3;
    uint32_t cb = sbs[k], cc = scnt[k];
    const unsigned long long* src = keys_raw + ((size_t)b * 64 + k) * CAP;
    for (uint32_t o = q; o < cc; o += 4) {
      uint32_t d = cb + o;
      if (d < (uint32_t)MMAX) sk[d] = src[o];
    }
  }
  for (int i = tid; i < MMAX; i += 256) if (i >= n) sk[i] = ~0ULL;
  __syncthreads();
  // rank my 64 candidates: each wave counts one 512-key window (broadcast reads)
  int c = r * 64 + lane;
  uint32_t partial = 0;
  if (c < n) {
    unsigned long long myk = sk[c];
    const ulonglong2* p2 = (const ulonglong2*)(sk + (size_t)wid * 512);
    for (int it = 0; it < 256; it += 4) {
      ulonglong2 a = p2[it], bq = p2[it + 1], cq = p2[it + 2], dq = p2[it + 3];
      partial += (uint32_t)(a.x < myk) + (uint32_t)(a.y < myk) +
                 (uint32_t)(bq.x < myk) + (uint32_t)(bq.y < myk) +
                 (uint32_t)(cq.x < myk) + (uint32_t)(cq.y < myk) +
                 (uint32_t)(dq.x < myk) + (uint32_t)(dq.y < myk);
    }
  }
  psum[wid * 64 + lane] = partial;
  __syncthreads();
  if (tid < 64) {
    int cc = r * 64 + tid;
    if (cc < n) {
      uint32_t rank = psum[tid] + psum[64 + tid] + psum[128 + tid] + psum[192 + tid];
      if (rank < (uint32_t)MMAX) {
        unsigned long long key = sk[cc];
        int i = (int)(uint32_t)key;
        float wmax = im_info[b * 3 + 1] - 1.0f;
        float hmax = im_info[b * 3 + 0] - 1.0f;
        float x1, y1, x2, y2;
        decode_box(anchors4, deltas4, b, i, wmax, hmax, x1, y1, x2, y2);
        sboxes[(size_t)b * MMAX + rank] = make_float4(x1, y1, x2, y2);
        slev[(size_t)b * MMAX + rank] = ids[i];
      }
    }
  }
}

// tiled all-pairs potential-suppressor detection. Same-level IoU is translation-
// invariant, so no level offset is needed here (cross-level pairs are skipped;
// they are provably disjoint under the reference's offset).
__global__ __launch_bounds__(64) void k_pairs(uint32_t* ctrs,
                                              const float4* __restrict__ sboxes,
                                              const int* __restrict__ slev,
                                              uint32_t* cnt2, int* suplist) {
  int b = blockIdx.y;
  int p = blockIdx.x;
  int tj = (int)((sqrtf(8.0f * (float)p + 1.0f) - 1.0f) * 0.5f);
  while ((tj + 1) * (tj + 2) / 2 <= p) ++tj;
  while (tj * (tj + 1) / 2 > p) --tj;
  int ti = p - tj * (tj + 1) / 2;
  int n = min((int)ctrs[b], MMAX);
  if (tj * 64 >= n) return;  // uniform across block
  int lane = threadIdx.x;

  __shared__ float4 ib[64];
  __shared__ int il[64];
  int ii = ti * 64 + lane;
  if (ii < n) {
    ib[lane] = sboxes[(size_t)b * MMAX + ii];
    il[lane] = slev[(size_t)b * MMAX + ii];
  } else {
    il[lane] = -1;
  }
  int j = tj * 64 + lane;
  float4 J = make_float4(0.f, 0.f, 0.f, 0.f);
  int jl = -2;
  float aj = 0.0f;
  if (j < n) {
    J = sboxes[(size_t)b * MMAX + j];
    jl = slev[(size_t)b * MMAX + j];
    aj = (J.z - J.x) * (J.w - J.y);
  }
  __syncthreads();
  if (j < n) {
    int imax = (ti == tj) ? lane : 64;  // diagonal: only i<j
    for (int k = 0; k < imax; ++k) {
      if (il[k] != jl) continue;
      float4 I = ib[k];
      float xx1 = fmaxf(I.x, J.x), yy1 = fmaxf(I.y, J.y);
      float xx2 = fminf(I.z, J.z), yy2 = fminf(I.w, J.w);
      float inter = fmaxf(xx2 - xx1, 0.0f) * fmaxf(yy2 - yy1, 0.0f);
      float ai = (I.z - I.x) * (I.w - I.y);
      float iou = inter / fmaxf((ai + aj) - inter, 1e-6f);
      if (iou > NMS_T) {
        uint32_t s = atomicAdd(&cnt2[(size_t)b * MMAX + j], 1u);
        if (s < (uint32_t)KSUP) suplist[((size_t)b * MMAX + j) * KSUP + s] = ti * 64 + k;
        else ctrs[8 + b] = 1u;  // suppressor-list overflow -> fallback
      }
    }
  }
}

// 1024-thread (16-wave) scan
__device__ __forceinline__ uint32_t scan_pair(uint32_t pairsum, volatile uint32_t* wsum,
                                              int tid, uint32_t* total_out) {
  int lane = tid & 63, wid = tid >> 6;
  uint32_t v = pairsum;
  for (int off = 1; off < 64; off <<= 1) {
    uint32_t u = __shfl_up(v, off, 64);
    if (lane >= off) v += u;
  }
  if (lane == 63) wsum[wid] = v;
  __syncthreads();
  if (tid == 0) {
    uint32_t run = 0;
    for (int w = 0; w < 16; ++w) { uint32_t t = wsum[w]; wsum[w] = run; run += t; }
    wsum[16] = run;
  }
  __syncthreads();
  uint32_t incl = v + wsum[wid];
  *total_out = wsum[16];
  return incl - pairsum;
}

// exact ordered resolution + compaction + output, with inline exact brute-force
// fallback (offset arithmetic exactly as reference) when any overflow occurred.
__global__ __launch_bounds__(1024) void k_out(const float* __restrict__ scores,
                                              const float4* __restrict__ deltas4,
                                              const float4* __restrict__ anchors4,
                                              const float* __restrict__ im_info,
                                              const int* __restrict__ ids,
                                              const uint32_t* __restrict__ ctrs,
                                              const uint32_t* __restrict__ cnt2,
                                              const int* __restrict__ suplist,
                                              const float4* __restrict__ sboxes,
                                              float* __restrict__ out) {
  int b = blockIdx.x;
  int tid = threadIdx.x;
  __shared__ uint8_t kept[MMAX];
  __shared__ uint32_t wsum[17];
  __shared__ uint16_t unc[UNC];
  __shared__ int supld[UNC][KSUP];
  __shared__ uint8_t supn[UNC];
  int n = min((int)ctrs[b], MMAX);
  int j0 = tid * 2, j1 = tid * 2 + 1;
  uint32_t c0 = (j0 < n) ? cnt2[(size_t)b * MMAX + j0] : 0u;
  uint32_t c1 = (j1 < n) ? cnt2[(size_t)b * MMAX + j1] : 0u;
  kept[j0] = (j0 < n && c0 == 0u) ? 1 : 0;
  kept[j1] = (j1 < n && c1 == 0u) ? 1 : 0;
  uint32_t u0 = (j0 < n && c0 > 0u) ? 1u : 0u;
  uint32_t u1 = (j1 < n && c1 > 0u) ? 1u : 0u;
  uint32_t tot_unc;
  uint32_t base = scan_pair(u0 + u1, wsum, tid, &tot_unc);
  if (u0) {
    uint32_t p = base;
    if (p < UNC) {
      int m = (int)min(c0, (uint32_t)KSUP);
      unc[p] = (uint16_t)j0; supn[p] = (uint8_t)m;
      for (int s = 0; s < m; ++s) supld[p][s] = suplist[((size_t)b * MMAX + j0) * KSUP + s];
    }
  }
  if (u1) {
    uint32_t p = base + u0;
    if (p < UNC) {
      int m = (int)min(c1, (uint32_t)KSUP);
      unc[p] = (uint16_t)j1; supn[p] = (uint8_t)m;
      for (int s = 0; s < m; ++s) supld[p][s] = suplist[((size_t)b * MMAX + j1) * KSUP + s];
    }
  }
  __syncthreads();
  if (tid < 64) {  // wave 0: exact greedy resolution in ascending rank order
    int nu = (int)min(tot_unc, (uint32_t)UNC);
    for (int u = 0; u < nu; ++u) {
      int m = (int)supn[u];
      int pred = (tid < m) ? (int)kept[supld[u][tid]] : 0;
      unsigned long long bal = __ballot(pred);
      if (tid == 0) kept[unc[u]] = (bal == 0ULL) ? 1 : 0;
    }
  }
  __syncthreads();
  uint32_t k0 = kept[j0], k1 = kept[j1];
  uint32_t total;
  uint32_t pbase = scan_pair(k0 + k1, wsum, tid, &total);
  if (k0 && pbase < (uint32_t)TOPN) {
    float4 bx = sboxes[(size_t)b * MMAX + j0];
    size_t o = ((size_t)b * TOPN + pbase) * 5;
    out[o] = (float)b; out[o+1] = bx.x; out[o+2] = bx.y; out[o+3] = bx.z; out[o+4] = bx.w;
  }
  if (k1) {
    uint32_t p = pbase + k0;
    if (p < (uint32_t)TOPN) {
      float4 bx = sboxes[(size_t)b * MMAX + j1];
      size_t o = ((size_t)b * TOPN + p) * 5;
      out[o] = (float)b; out[o+1] = bx.x; out[o+2] = bx.y; out[o+3] = bx.z; out[o+4] = bx.w;
    }
  }
  for (int t = tid; t < TOPN; t += 1024) {
    if ((uint32_t)t >= total) {
      size_t o = ((size_t)b * TOPN + t) * 5;
      out[o] = (float)b; out[o+1] = 0.0f; out[o+2] = 0.0f; out[o+3] = 0.0f; out[o+4] = 0.0f;
    }
  }

  bool needFB = (ctrs[8 + b] != 0u) || (total < (uint32_t)TOPN) || (tot_unc > (uint32_t)UNC);
  if (!needFB) return;

  // ---------- exact brute-force fallback (block-uniform path) ----------
  __shared__ uint32_t mask[NB / 32];
  __shared__ float rv[1024];
  __shared__ int ri[1024];
  __shared__ float fm[16];
  const float wmax = im_info[b * 3 + 1] - 1.0f;
  const float hmax = im_info[b * 3 + 0] - 1.0f;
  __syncthreads();  // order resolve-phase out writes before overwrite
  // exact max over all clipped coords (matches jnp.max(boxes))
  float mx = 0.0f;
  for (int i = tid; i < NB; i += 1024) {
    float x1, y1, x2, y2;
    decode_box(anchors4, deltas4, b, i, wmax, hmax, x1, y1, x2, y2);
    mx = fmaxf(mx, fmaxf(fmaxf(x1, y1), fmaxf(x2, y2)));
  }
  for (int o = 32; o > 0; o >>= 1) mx = fmaxf(mx, __shfl_xor(mx, o, 64));
  if ((tid & 63) == 0) fm[tid >> 6] = mx;
  __syncthreads();
  if (tid == 0) {
    float m = fm[0];
    for (int w = 1; w < 16; ++w) m = fmaxf(m, fm[w]);
    fm[0] = m;
  }
  for (int i = tid; i < NB / 32; i += 1024) mask[i] = 0u;
  __syncthreads();
  float max_c = fm[0] + 1.0f;
  for (int it = 0; it < TOPN; ++it) {
    float bv = -3e38f; int bi = 0x7fffffff;
    for (int i = tid; i < NB; i += 1024) {
      bool sup = (mask[i >> 5] >> (i & 31)) & 1u;
      float v = sup ? NEGV : scores[(size_t)b * NB + i];
      if (v > bv || (v == bv && i < bi)) { bv = v; bi = i; }
    }
    rv[tid] = bv; ri[tid] = bi;
    __syncthreads();
    for (int s = 512; s > 0; s >>= 1) {
      if (tid < s) {
        float v2 = rv[tid + s]; int i2 = ri[tid + s];
        if (v2 > rv[tid] || (v2 == rv[tid] && i2 < ri[tid])) { rv[tid] = v2; ri[tid] = i2; }
      }
      __syncthreads();
    }
    int ii = ri[0]; float vv = rv[0];
    bool valid = vv > NEGV * 0.5f;
    if (!valid) {
      if (tid == 0) {
        size_t o = ((size_t)b * TOPN + it) * 5;
        out[o] = (float)b; out[o+1] = 0; out[o+2] = 0; out[o+3] = 0; out[o+4] = 0;
      }
      __syncthreads();
      continue;
    }
    float x1, y1, x2, y2;
    decode_box(anchors4, deltas4, b, ii, wmax, hmax, x1, y1, x2, y2);
    int lv = ids[ii];
    float off = (float)lv * max_c;
    float s0 = x1 + off, s1 = y1 + off, s2 = x2 + off, s3 = y2 + off;
    float a1 = (s2 - s0) * (s3 - s1);
    if (tid == 0) {
      size_t o = ((size_t)b * TOPN + it) * 5;
      out[o] = (float)b; out[o+1] = x1; out[o+2] = y1; out[o+3] = x2; out[o+4] = y2;
    }
    for (int j = tid; j < NB; j += 1024) {
      if ((mask[j >> 5] >> (j & 31)) & 1u) continue;
      if (ids[j] != lv) continue;  // cross-level IoU exactly 0 under offset geometry
      float bx1, by1, bx2, by2;
      decode_box(anchors4, deltas4, b, j, wmax, hmax, bx1, by1, bx2, by2);
      float t0 = bx1 + off, t1 = by1 + off, t2 = bx2 + off, t3 = by2 + off;
      float xx1 = fmaxf(s0, t0), yy1 = fmaxf(s1, t1);
      float xx2 = fminf(s2, t2), yy2 = fminf(s3, t3);
      float inter = fmaxf(xx2 - xx1, 0.0f) * fmaxf(yy2 - yy1, 0.0f);
      float a2r = (t2 - t0) * (t3 - t1);
      float iou = inter / fmaxf(a1 + a2r - inter, 1e-6f);
      if (iou > NMS_T) atomicOr(&mask[j >> 5], 1u << (j & 31));
    }
    if (tid == 0) atomicOr(&mask[ii >> 5], 1u << (ii & 31));
    __syncthreads();
  }
}

extern "C" void kernel_launch(void* const* d_in, const int* in_sizes, int n_in,
                              void* d_out, int out_size, void* d_ws, size_t ws_size,
                              hipStream_t stream) {
  const float*  scores   = (const float*)d_in[0];
  const float4* deltas4  = (const float4*)d_in[1];
  const float4* anchors4 = (const float4*)d_in[2];
  const float*  im_info  = (const float*)d_in[3];
  const int*    ids      = (const int*)d_in[4];
  float* out = (float*)d_out;

  char* ws = (char*)d_ws;
  uint32_t*           ctrs     = (uint32_t*)ws;
  uint32_t*           cnt_blk  = (uint32_t*)(ws + OFF_CBLK);
  unsigned long long* keys_raw = (unsigned long long*)(ws + OFF_KRAW);
  float4*             sboxes   = (float4*)(ws + OFF_SBOX);
  int*                slev     = (int*)(ws + OFF_SLEV);
  uint32_t*           cnt2     = (uint32_t*)(ws + OFF_CNT2);
  int*                suplist  = (int*)(ws + OFF_SUP);

  hipLaunchKernelGGL(k_prep, dim3(64 * BATCH), dim3(256), 0, stream,
                     scores, keys_raw, cnt_blk);
  hipLaunchKernelGGL(k_rank, dim3(NTILE, BATCH), dim3(256), 0, stream,
                     cnt_blk, keys_raw, deltas4, anchors4, im_info, ids,
                     ctrs, sboxes, slev, cnt2);
  hipLaunchKernelGGL(k_pairs, dim3(NPAIRS, BATCH), dim3(64), 0, stream,
                     ctrs, sboxes, slev, cnt2, suplist);
  hipLaunchKernelGGL(k_out, dim3(BATCH), dim3(1024), 0, stream,
                     scores, deltas4, anchors4, im_info, ids, ctrs, cnt2, suplist,
                     sboxes, out);
}